// Round 3
// 125.667 us; speedup vs baseline: 1.0129x; 1.0129x over previous
//
#include <hip/hip_runtime.h>
#include <hip/hip_fp16.h>

#define NN 50000
#define NE 800000
#define IN_DIM 128
#define OUT_DIM 64
#define NEG 0.2f

#define BSHIFT 7
#define BNODES 128              // nodes per bucket
#define NBUCK 391               // ceil(50000 / 128)
#define HALFCAP 2560            // window per bucket: mean 2048, +11 sigma
#define CHUNK 4096              // edges per bin block
#define BIN_BLOCKS 196          // ceil(NE / CHUNK)
#define GEMM_BLOCKS 391         // ceil(NN / 128)

#define XS_STRIDE 136           // bf16 elems/row: 272 B, 16B-aligned

typedef short short8 __attribute__((ext_vector_type(8)));
typedef float f32x4 __attribute__((ext_vector_type(4)));

__device__ __forceinline__ unsigned short f2bf(float f) {
    unsigned u = __float_as_uint(f);
    u += 0x7FFFu + ((u >> 16) & 1u);
    return (unsigned short)(u >> 16);
}

// ---- Kernel 0: zero the bucket cursors (pure-kernel graph) -----------------
__global__ __launch_bounds__(512) void gat_zero(int* __restrict__ bucket_cur) {
    if (threadIdx.x < NBUCK) bucket_cur[threadIdx.x] = 0;
}

// ---- Kernel A (512 threads): fused [edge bin-sort] (blocks 0..195, first)
//      and [h2 = fp16(x@W) via bf16 MFMA, 128-row tiles] --------------------
__global__ __launch_bounds__(512) void gat_gemm_bin(
    const float* __restrict__ x, const float* __restrict__ W,
    const float* __restrict__ att_src, const float* __restrict__ att_dst,
    const int* __restrict__ src, const int* __restrict__ dst,
    unsigned short* __restrict__ h2, float* __restrict__ a_src,
    float* __restrict__ a_dst,
    int* __restrict__ gbucket, int* __restrict__ bucket_cur)
{
    __shared__ __align__(16) unsigned short xs[128 * XS_STRIDE]; // 34816 B
    __shared__ __align__(16) unsigned short wt[64 * XS_STRIDE];  // 17408 B
    const int tid = threadIdx.x;
    const int lane = tid & 63, wid = tid >> 6;

    if (blockIdx.x < BIN_BLOCKS) {
        // ---------------- bin sort, single global pass ----------------
        // record = {bkt:9 | src:16 | dlow:7}
        int* recs_in  = (int*)xs;            // [CHUNK] 16 KB
        int* bcnt     = recs_in + CHUNK;     // [512]
        int* cur      = bcnt + 512;          // [512]
        int* lbase    = cur + 512;           // [512]
        int* comb     = lbase + 512;         // [512]
        int* wsum     = comb + 512;          // [8]
        int* recs_out = (int*)wt;            // [CHUNK] 16 KB
        const int e0 = blockIdx.x * CHUNK;
        const int total = (e0 + CHUNK < NE ? CHUNK : NE - e0);

        bcnt[tid] = 0;
        __syncthreads();
#pragma unroll
        for (int k = 0; k < CHUNK / 512; ++k) {
            const int e = e0 + k * 512 + tid;
            if (e < NE) {
                const int d = dst[e];
                const int bkt = d >> BSHIFT;
                recs_in[k * 512 + tid] =
                    (bkt << 23) | (src[e] << BSHIFT) | (d & (BNODES - 1));
                atomicAdd(&bcnt[bkt], 1);
            }
        }
        __syncthreads();
        // wave-shuffle scan of bcnt (512 entries, 8 waves, 2 barriers)
        const int v = bcnt[tid];
        int incl = v;
#pragma unroll
        for (int off = 1; off < 64; off <<= 1) {
            const int n = __shfl_up(incl, off, 64);
            if (lane >= off) incl += n;
        }
        if (lane == 63) wsum[wid] = incl;
        __syncthreads();
        int wpre = 0;
#pragma unroll
        for (int w = 0; w < 8; ++w)
            if (w < wid) wpre += wsum[w];
        const int excl = wpre + incl - v;
        lbase[tid] = excl; cur[tid] = excl;
        int gb = 0;
        if (tid < NBUCK && v) gb = atomicAdd(&bucket_cur[tid], v);
        comb[tid] = gb - excl;
        __syncthreads();
        // place (LDS -> LDS, grouped by bucket)
#pragma unroll
        for (int k = 0; k < CHUNK / 512; ++k) {
            const int idx = k * 512 + tid;
            if (idx < total) {
                const int r = recs_in[idx];
                const unsigned bkt = (unsigned)r >> 23;
                const int pos = atomicAdd(&cur[bkt], 1);
                recs_out[pos] = r;
            }
        }
        __syncthreads();
        // coalesced flush
        for (int j = tid; j < total; j += 512) {
            const int r = recs_out[j];
            const unsigned bkt = (unsigned)r >> 23;
            const int rel = comb[bkt] + j;
            if (rel < HALFCAP)
                gbucket[bkt * HALFCAP + rel] = r & 0x7FFFFF;
        }
        return;
    }

    // ---------------- GEMM path: bf16 MFMA, 128x64 tile, 8 waves -------
    const int block_row = (blockIdx.x - BIN_BLOCKS) * 128;

    for (int t = tid; t < 128 * 32; t += 512) {
        const int r = t >> 5, k = (t & 31) << 2;
        const int row = block_row + r;
        float4 v = make_float4(0.f, 0.f, 0.f, 0.f);
        if (row < NN) v = *(const float4*)(x + (size_t)row * IN_DIM + k);
        ushort4 p;
        p.x = f2bf(v.x); p.y = f2bf(v.y); p.z = f2bf(v.z); p.w = f2bf(v.w);
        *(ushort4*)&xs[r * XS_STRIDE + k] = p;
    }
    for (int t = tid; t < 128 * 16; t += 512) {
        const int k = t >> 4, n4 = (t & 15) << 2;
        const float4 v = *(const float4*)(W + k * 64 + n4);
        wt[(n4 + 0) * XS_STRIDE + k] = f2bf(v.x);
        wt[(n4 + 1) * XS_STRIDE + k] = f2bf(v.y);
        wt[(n4 + 2) * XS_STRIDE + k] = f2bf(v.z);
        wt[(n4 + 3) * XS_STRIDE + k] = f2bf(v.w);
    }
    __syncthreads();

    const int m = lane & 15, quad = lane >> 4;

    f32x4 acc[4];
#pragma unroll
    for (int ct = 0; ct < 4; ++ct) acc[ct] = (f32x4){0.f, 0.f, 0.f, 0.f};

    const unsigned short* xrow = &xs[(wid * 16 + m) * XS_STRIDE + quad * 8];
#pragma unroll
    for (int kt = 0; kt < 4; ++kt) {
        short8 af = *(const short8*)(xrow + kt * 32);
#pragma unroll
        for (int ct = 0; ct < 4; ++ct) {
            short8 bf = *(const short8*)(&wt[(ct * 16 + m) * XS_STRIDE + kt * 32 + quad * 8]);
            acc[ct] = __builtin_amdgcn_mfma_f32_16x16x32_bf16(af, bf, acc[ct], 0, 0, 0);
        }
    }

    float as_c[4], ad_c[4];
#pragma unroll
    for (int ct = 0; ct < 4; ++ct) {
        as_c[ct] = att_src[ct * 16 + m];
        ad_c[ct] = att_dst[ct * 16 + m];
    }
    float ps[4], pd[4];
#pragma unroll
    for (int reg = 0; reg < 4; ++reg) {
        float s = 0.f, d = 0.f;
#pragma unroll
        for (int ct = 0; ct < 4; ++ct) {
            s += acc[ct][reg] * as_c[ct];
            d += acc[ct][reg] * ad_c[ct];
        }
        ps[reg] = s; pd[reg] = d;
    }
#pragma unroll
    for (int off = 1; off < 16; off <<= 1) {
#pragma unroll
        for (int reg = 0; reg < 4; ++reg) {
            ps[reg] += __shfl_xor(ps[reg], off, 64);
            pd[reg] += __shfl_xor(pd[reg], off, 64);
        }
    }
    if (m == 0) {
#pragma unroll
        for (int reg = 0; reg < 4; ++reg) {
            const int row = block_row + wid * 16 + quad * 4 + reg;
            if (row < NN) { a_src[row] = ps[reg]; a_dst[row] = pd[reg]; }
        }
    }

    __syncthreads();
    unsigned short* hs = xs;               // 128 rows x stride 72
#pragma unroll
    for (int ct = 0; ct < 4; ++ct)
#pragma unroll
        for (int reg = 0; reg < 4; ++reg)
            hs[(wid * 16 + quad * 4 + reg) * 72 + ct * 16 + m] =
                __half_as_ushort(__float2half(acc[ct][reg]));
    __syncthreads();
    {
        const int r = tid >> 2, c = (tid & 3) * 16;
        const int row = block_row + r;
        if (row < NN) {
            uint4 v0 = *(const uint4*)&hs[r * 72 + c];
            uint4 v1 = *(const uint4*)&hs[r * 72 + c + 8];
            *(uint4*)(h2 + (size_t)row * 64 + c) = v0;
            *(uint4*)(h2 + (size_t)row * 64 + c + 8) = v1;
        }
    }
}

// ---- Kernel B: FUSED per-bucket counting sort (LDS) + exp + aggregation ----
// 391 blocks (one per 128-node bucket), 1024 threads.
__global__ __launch_bounds__(1024) void gat_sortagg(
    const int* __restrict__ gbucket, const int* __restrict__ bucket_cur,
    const __half* __restrict__ h2, const float* __restrict__ a_src,
    const float* __restrict__ a_dst, const float* __restrict__ bias,
    float* __restrict__ out)
{
    __shared__ int raw[HALFCAP];                 // 10.2 KB
    __shared__ unsigned srtex[HALFCAP];          // 10.2 KB packed {ex, src}
    __shared__ int hist[BNODES];
    __shared__ int scanb[BNODES];
    __shared__ int cur[BNODES];
    __shared__ float ads[BNODES];
    __shared__ float ass[BNODES];                // own-node a_src cache
    __shared__ int wsum[2];
    const int b = blockIdx.x;
    const int tid = threadIdx.x;
    const int node0 = b << BSHIFT;

    int cnt_b = bucket_cur[b];
    if (cnt_b > HALFCAP) cnt_b = HALFCAP;
    const int* win = gbucket + (size_t)b * HALFCAP;

    if (tid < BNODES) {
        hist[tid] = 0;
        const int n = node0 + tid;
        ads[tid] = (n < NN) ? a_dst[n] : 0.f;
        ass[tid] = (n < NN) ? a_src[n] : 0.f;
    }
    __syncthreads();
    for (int i = tid; i < cnt_b; i += 1024) {
        const int r = win[i];
        raw[i] = r;
        atomicAdd(&hist[r & (BNODES - 1)], 1);
    }
    __syncthreads();
    // wave-shuffle scan of hist (128 entries, 2 waves, 2 barriers)
    const int lane = tid & 63;
    int v = 0, incl = 0;
    if (tid < BNODES) {
        v = hist[tid];
        incl = v;
#pragma unroll
        for (int off = 1; off < 64; off <<= 1) {
            const int n = __shfl_up(incl, off, 64);
            if (lane >= off) incl += n;
        }
        if (lane == 63) wsum[tid >> 6] = incl;
    }
    __syncthreads();
    if (tid < BNODES) {
        const int inclT = incl + ((tid >= 64) ? wsum[0] : 0);
        scanb[tid] = inclT;
        cur[tid] = inclT - v;
    }
    __syncthreads();
    for (int i = tid; i < cnt_b; i += 1024) {
        const int r = raw[i];
        const int dl = r & (BNODES - 1);
        const int s = (r >> BSHIFT) & 0xFFFF;
        float ev = a_src[s] + ads[dl];
        ev = ev > 0.f ? ev : NEG * ev;
        const float ex = __expf(ev);
        const int pos = atomicAdd(&cur[dl], 1);
        srtex[pos] = (unsigned)s |
                     ((unsigned)__half_as_ushort(__float2half(ex)) << 16);
    }
    __syncthreads();

    const int wid = tid >> 6;
    const int grp = lane >> 3;      // edge slot 0..7
    const int cq = lane & 7;        // 16B column oct

    for (int k = 0; k < 8; ++k) {
        const int ln = k * 16 + wid;            // 0..127
        const int node = node0 + ln;
        if (node >= NN) break;
        const int deg = hist[ln];
        const int rbase = scanb[ln] - deg;

        // self logit entirely from LDS (no dependent global gather)
        float v2 = ass[ln] + ads[ln];
        v2 = v2 > 0.f ? v2 : NEG * v2;
        const float exs = __expf(v2);
        const float w0 = (grp == 0) ? exs : 0.f;

        // Issue self row + BOTH first chunks back-to-back (two-deep prefetch).
        // For deg <= 16 (majority), all global loads for this node are in
        // flight before any consumption -> one exposed L2 latency, not two.
        uint4 hp = *(const uint4*)(h2 + ((size_t)node << 6) + (cq << 3));

        int   sA = -1; float eA = 0.f; uint4 gA = make_uint4(0, 0, 0, 0);
        int   sB = -1; float eB = 0.f; uint4 gB = make_uint4(0, 0, 0, 0);
        if (grp < deg) {
            const unsigned p = srtex[rbase + grp];
            sA = (int)(p & 0xffffu);
            eA = __half2float(__ushort_as_half((unsigned short)(p >> 16)));
            gA = *(const uint4*)(h2 + ((size_t)sA << 6) + (cq << 3));
        }
        if (8 + grp < deg) {
            const unsigned p = srtex[rbase + 8 + grp];
            sB = (int)(p & 0xffffu);
            eB = __half2float(__ushort_as_half((unsigned short)(p >> 16)));
            gB = *(const uint4*)(h2 + ((size_t)sB << 6) + (cq << 3));
        }

        float acc[8];
        {
            const __half2* hh = (const __half2*)&hp;
#pragma unroll
            for (int j = 0; j < 4; ++j) {
                float2 f = __half22float2(hh[j]);
                acc[2 * j] = w0 * f.x;
                acc[2 * j + 1] = w0 * f.y;
            }
        }
        float den = w0;

        // rolling 2-deep pipeline: consume chunk at `base` (in A),
        // prefetch chunk at `base+16` into C, rotate A<-B<-C.
        for (int base = 0; base < deg; base += 8) {
            int sC = -1; float eC = 0.f; uint4 gC = make_uint4(0, 0, 0, 0);
            const int en = base + 16 + grp;
            if (en < deg) {
                const unsigned p = srtex[rbase + en];
                sC = (int)(p & 0xffffu);
                eC = __half2float(__ushort_as_half((unsigned short)(p >> 16)));
                gC = *(const uint4*)(h2 + ((size_t)sC << 6) + (cq << 3));
            }
            if (sA >= 0) {
                const __half2* gh = (const __half2*)&gA;
#pragma unroll
                for (int j = 0; j < 4; ++j) {
                    float2 f = __half22float2(gh[j]);
                    acc[2 * j] += eA * f.x;
                    acc[2 * j + 1] += eA * f.y;
                }
                den += eA;
            }
            sA = sB; eA = eB; gA = gB;
            sB = sC; eB = eC; gB = gC;
        }

#pragma unroll
        for (int off = 8; off < 64; off <<= 1) {
#pragma unroll
            for (int j = 0; j < 8; ++j) acc[j] += __shfl_xor(acc[j], off, 64);
            den += __shfl_xor(den, off, 64);
        }

        if (grp == 0) {
            const float inv = 1.f / den;
            const float4 b0 = *(const float4*)(bias + (cq << 3));
            const float4 b1 = *(const float4*)(bias + (cq << 3) + 4);
            float4 o0, o1;
            o0.x = acc[0] * inv + b0.x; o0.y = acc[1] * inv + b0.y;
            o0.z = acc[2] * inv + b0.z; o0.w = acc[3] * inv + b0.w;
            o1.x = acc[4] * inv + b1.x; o1.y = acc[5] * inv + b1.y;
            o1.z = acc[6] * inv + b1.z; o1.w = acc[7] * inv + b1.w;
            float* op = out + ((size_t)node << 6) + (cq << 3);
            *(float4*)op = o0;
            *(float4*)(op + 4) = o1;
        }
    }
}

extern "C" void kernel_launch(void* const* d_in, const int* in_sizes, int n_in,
                              void* d_out, int out_size, void* d_ws, size_t ws_size,
                              hipStream_t stream) {
    const float* x       = (const float*)d_in[0];
    const int*   eidx    = (const int*)d_in[1];   // [2, NE] row-major
    const float* W       = (const float*)d_in[2];
    const float* att_src = (const float*)d_in[3];
    const float* att_dst = (const float*)d_in[4];
    const float* bias    = (const float*)d_in[5];
    float* out = (float*)d_out;

    // ws: h2 [NN*64 fp16 = 6.4MB] | gbucket [391*2560*4 = 4.0MB]
    //   | a_src [NN] | a_dst [NN] | bucket_cur [NBUCK]
    unsigned short* h2 = (unsigned short*)d_ws;
    int*   gbucket = (int*)((char*)d_ws + (size_t)NN * OUT_DIM * 2);
    float* a_src   = (float*)(gbucket + (size_t)NBUCK * HALFCAP);
    float* a_dst   = a_src + NN;
    int*   bucket_cur = (int*)(a_dst + NN);

    const int* src = eidx;
    const int* dst = eidx + NE;

    gat_zero<<<1, 512, 0, stream>>>(bucket_cur);
    gat_gemm_bin<<<GEMM_BLOCKS + BIN_BLOCKS, 512, 0, stream>>>(
        x, W, att_src, att_dst, src, dst, h2, a_src, a_dst, gbucket, bucket_cur);
    gat_sortagg<<<NBUCK, 1024, 0, stream>>>(
        gbucket, bucket_cur, (const __half*)h2, a_src, a_dst, bias, out);
}

// Round 4
// 113.131 us; speedup vs baseline: 1.1251x; 1.1108x over previous
//
#include <hip/hip_runtime.h>
#include <hip/hip_fp16.h>

#define NN 50000
#define NE 800000
#define IN_DIM 128
#define OUT_DIM 64
#define NEG 0.2f

#define BSHIFT 7
#define BNODES 128              // nodes per bucket
#define NBUCK 391               // ceil(50000 / 128)
#define HALFCAP 2560            // window per bucket: mean 2048, +11 sigma
#define CHUNK 4096              // edges per bin block
#define BIN_BLOCKS 196          // ceil(NE / CHUNK)
#define GEMM_BLOCKS 391         // ceil(NN / 128)

#define XS_STRIDE 136           // bf16 elems/row: 272 B, 16B-aligned

typedef short short8 __attribute__((ext_vector_type(8)));
typedef float f32x4 __attribute__((ext_vector_type(4)));

__device__ __forceinline__ unsigned short f2bf(float f) {
    unsigned u = __float_as_uint(f);
    u += 0x7FFFu + ((u >> 16) & 1u);
    return (unsigned short)(u >> 16);
}

// ---- Kernel 0: zero the bucket cursors (pure-kernel graph) -----------------
__global__ __launch_bounds__(512) void gat_zero(int* __restrict__ bucket_cur) {
    if (threadIdx.x < NBUCK) bucket_cur[threadIdx.x] = 0;
}

// ---- Kernel A (512 threads): fused [edge bin-sort] (blocks 0..195, first)
//      and [h2 = fp16(x@W) via bf16 MFMA, 128-row tiles] --------------------
__global__ __launch_bounds__(512) void gat_gemm_bin(
    const float* __restrict__ x, const float* __restrict__ W,
    const float* __restrict__ att_src, const float* __restrict__ att_dst,
    const int* __restrict__ src, const int* __restrict__ dst,
    unsigned short* __restrict__ h2, float* __restrict__ a_src,
    float* __restrict__ a_dst,
    int* __restrict__ gbucket, int* __restrict__ bucket_cur)
{
    __shared__ __align__(16) unsigned short xs[128 * XS_STRIDE]; // 34816 B
    __shared__ __align__(16) unsigned short wt[64 * XS_STRIDE];  // 17408 B
    const int tid = threadIdx.x;
    const int lane = tid & 63, wid = tid >> 6;

    if (blockIdx.x < BIN_BLOCKS) {
        // ---------------- bin sort, single global pass ----------------
        // record = {bkt:9 | src:16 | dlow:7}
        int* recs_in  = (int*)xs;            // [CHUNK] 16 KB
        int* bcnt     = recs_in + CHUNK;     // [512]
        int* cur      = bcnt + 512;          // [512]
        int* lbase    = cur + 512;           // [512]
        int* comb     = lbase + 512;         // [512]
        int* wsum     = comb + 512;          // [8]
        int* recs_out = (int*)wt;            // [CHUNK] 16 KB
        const int e0 = blockIdx.x * CHUNK;
        const int total = (e0 + CHUNK < NE ? CHUNK : NE - e0);

        bcnt[tid] = 0;
        __syncthreads();
#pragma unroll
        for (int k = 0; k < CHUNK / 512; ++k) {
            const int e = e0 + k * 512 + tid;
            if (e < NE) {
                const int d = dst[e];
                const int bkt = d >> BSHIFT;
                recs_in[k * 512 + tid] =
                    (bkt << 23) | (src[e] << BSHIFT) | (d & (BNODES - 1));
                atomicAdd(&bcnt[bkt], 1);
            }
        }
        __syncthreads();
        // wave-shuffle scan of bcnt (512 entries, 8 waves, 2 barriers)
        const int v = bcnt[tid];
        int incl = v;
#pragma unroll
        for (int off = 1; off < 64; off <<= 1) {
            const int n = __shfl_up(incl, off, 64);
            if (lane >= off) incl += n;
        }
        if (lane == 63) wsum[wid] = incl;
        __syncthreads();
        int wpre = 0;
#pragma unroll
        for (int w = 0; w < 8; ++w)
            if (w < wid) wpre += wsum[w];
        const int excl = wpre + incl - v;
        lbase[tid] = excl; cur[tid] = excl;
        int gb = 0;
        if (tid < NBUCK && v) gb = atomicAdd(&bucket_cur[tid], v);
        comb[tid] = gb - excl;
        __syncthreads();
        // place (LDS -> LDS, grouped by bucket)
#pragma unroll
        for (int k = 0; k < CHUNK / 512; ++k) {
            const int idx = k * 512 + tid;
            if (idx < total) {
                const int r = recs_in[idx];
                const unsigned bkt = (unsigned)r >> 23;
                const int pos = atomicAdd(&cur[bkt], 1);
                recs_out[pos] = r;
            }
        }
        __syncthreads();
        // coalesced flush
        for (int j = tid; j < total; j += 512) {
            const int r = recs_out[j];
            const unsigned bkt = (unsigned)r >> 23;
            const int rel = comb[bkt] + j;
            if (rel < HALFCAP)
                gbucket[bkt * HALFCAP + rel] = r & 0x7FFFFF;
        }
        return;
    }

    // ---------------- GEMM path: bf16 MFMA, 128x64 tile, 8 waves -------
    const int block_row = (blockIdx.x - BIN_BLOCKS) * 128;

    for (int t = tid; t < 128 * 32; t += 512) {
        const int r = t >> 5, k = (t & 31) << 2;
        const int row = block_row + r;
        float4 v = make_float4(0.f, 0.f, 0.f, 0.f);
        if (row < NN) v = *(const float4*)(x + (size_t)row * IN_DIM + k);
        ushort4 p;
        p.x = f2bf(v.x); p.y = f2bf(v.y); p.z = f2bf(v.z); p.w = f2bf(v.w);
        *(ushort4*)&xs[r * XS_STRIDE + k] = p;
    }
    for (int t = tid; t < 128 * 16; t += 512) {
        const int k = t >> 4, n4 = (t & 15) << 2;
        const float4 v = *(const float4*)(W + k * 64 + n4);
        wt[(n4 + 0) * XS_STRIDE + k] = f2bf(v.x);
        wt[(n4 + 1) * XS_STRIDE + k] = f2bf(v.y);
        wt[(n4 + 2) * XS_STRIDE + k] = f2bf(v.z);
        wt[(n4 + 3) * XS_STRIDE + k] = f2bf(v.w);
    }
    __syncthreads();

    const int m = lane & 15, quad = lane >> 4;

    f32x4 acc[4];
#pragma unroll
    for (int ct = 0; ct < 4; ++ct) acc[ct] = (f32x4){0.f, 0.f, 0.f, 0.f};

    const unsigned short* xrow = &xs[(wid * 16 + m) * XS_STRIDE + quad * 8];
#pragma unroll
    for (int kt = 0; kt < 4; ++kt) {
        short8 af = *(const short8*)(xrow + kt * 32);
#pragma unroll
        for (int ct = 0; ct < 4; ++ct) {
            short8 bf = *(const short8*)(&wt[(ct * 16 + m) * XS_STRIDE + kt * 32 + quad * 8]);
            acc[ct] = __builtin_amdgcn_mfma_f32_16x16x32_bf16(af, bf, acc[ct], 0, 0, 0);
        }
    }

    float as_c[4], ad_c[4];
#pragma unroll
    for (int ct = 0; ct < 4; ++ct) {
        as_c[ct] = att_src[ct * 16 + m];
        ad_c[ct] = att_dst[ct * 16 + m];
    }
    float ps[4], pd[4];
#pragma unroll
    for (int reg = 0; reg < 4; ++reg) {
        float s = 0.f, d = 0.f;
#pragma unroll
        for (int ct = 0; ct < 4; ++ct) {
            s += acc[ct][reg] * as_c[ct];
            d += acc[ct][reg] * ad_c[ct];
        }
        ps[reg] = s; pd[reg] = d;
    }
#pragma unroll
    for (int off = 1; off < 16; off <<= 1) {
#pragma unroll
        for (int reg = 0; reg < 4; ++reg) {
            ps[reg] += __shfl_xor(ps[reg], off, 64);
            pd[reg] += __shfl_xor(pd[reg], off, 64);
        }
    }
    if (m == 0) {
#pragma unroll
        for (int reg = 0; reg < 4; ++reg) {
            const int row = block_row + wid * 16 + quad * 4 + reg;
            if (row < NN) { a_src[row] = ps[reg]; a_dst[row] = pd[reg]; }
        }
    }

    __syncthreads();
    unsigned short* hs = xs;               // 128 rows x stride 72
#pragma unroll
    for (int ct = 0; ct < 4; ++ct)
#pragma unroll
        for (int reg = 0; reg < 4; ++reg)
            hs[(wid * 16 + quad * 4 + reg) * 72 + ct * 16 + m] =
                __half_as_ushort(__float2half(acc[ct][reg]));
    __syncthreads();
    {
        const int r = tid >> 2, c = (tid & 3) * 16;
        const int row = block_row + r;
        if (row < NN) {
            uint4 v0 = *(const uint4*)&hs[r * 72 + c];
            uint4 v1 = *(const uint4*)&hs[r * 72 + c + 8];
            *(uint4*)(h2 + (size_t)row * 64 + c) = v0;
            *(uint4*)(h2 + (size_t)row * 64 + c + 8) = v1;
        }
    }
}

// ---- Kernel B: FUSED per-bucket counting sort (LDS) + exp + aggregation ----
// 391 blocks (one per 128-node bucket), 1024 threads.
// Phase 4: node-per-lane-group (8 lanes/node) — no serial node loop, no
// cross-lane reductions; each lane owns 8 output columns of one node.
__global__ __launch_bounds__(1024) void gat_sortagg(
    const int* __restrict__ gbucket, const int* __restrict__ bucket_cur,
    const __half* __restrict__ h2, const float* __restrict__ a_src,
    const float* __restrict__ a_dst, const float* __restrict__ bias,
    float* __restrict__ out)
{
    __shared__ int raw[HALFCAP];                 // 10.2 KB
    __shared__ unsigned srtex[HALFCAP];          // 10.2 KB packed {ex, src}
    __shared__ int hist[BNODES];
    __shared__ int scanb[BNODES];
    __shared__ int cur[BNODES];
    __shared__ float ads[BNODES];
    __shared__ float ass[BNODES];                // own-node a_src cache
    __shared__ int wsum[2];
    const int b = blockIdx.x;
    const int tid = threadIdx.x;
    const int node0 = b << BSHIFT;

    int cnt_b = bucket_cur[b];
    if (cnt_b > HALFCAP) cnt_b = HALFCAP;
    const int* win = gbucket + (size_t)b * HALFCAP;

    if (tid < BNODES) {
        hist[tid] = 0;
        const int n = node0 + tid;
        ads[tid] = (n < NN) ? a_dst[n] : 0.f;
        ass[tid] = (n < NN) ? a_src[n] : 0.f;
    }
    __syncthreads();
    for (int i = tid; i < cnt_b; i += 1024) {
        const int r = win[i];
        raw[i] = r;
        atomicAdd(&hist[r & (BNODES - 1)], 1);
    }
    __syncthreads();
    // wave-shuffle scan of hist (128 entries, 2 waves, 2 barriers)
    const int lane = tid & 63;
    int v = 0, incl = 0;
    if (tid < BNODES) {
        v = hist[tid];
        incl = v;
#pragma unroll
        for (int off = 1; off < 64; off <<= 1) {
            const int n = __shfl_up(incl, off, 64);
            if (lane >= off) incl += n;
        }
        if (lane == 63) wsum[tid >> 6] = incl;
    }
    __syncthreads();
    if (tid < BNODES) {
        const int inclT = incl + ((tid >= 64) ? wsum[0] : 0);
        scanb[tid] = inclT;
        cur[tid] = inclT - v;
    }
    __syncthreads();
    for (int i = tid; i < cnt_b; i += 1024) {
        const int r = raw[i];
        const int dl = r & (BNODES - 1);
        const int s = (r >> BSHIFT) & 0xFFFF;
        float ev = a_src[s] + ads[dl];
        ev = ev > 0.f ? ev : NEG * ev;
        const float ex = __expf(ev);
        const int pos = atomicAdd(&cur[dl], 1);
        srtex[pos] = (unsigned)s |
                     ((unsigned)__half_as_ushort(__float2half(ex)) << 16);
    }
    __syncthreads();

    // ---------------- phase 4: node-per-lane-group aggregation -------------
    // 1024 threads = 128 groups of 8 lanes; group g owns node node0+g,
    // lane (tid&7) owns columns [8*(tid&7) .. 8*(tid&7)+7].  All 128 nodes
    // processed in ONE pass: no serial node loop, no shuffle reductions.
    {
        const int g  = tid >> 3;        // node slot 0..127
        const int cq = tid & 7;         // 16B column slice
        const int node = node0 + g;
        if (node < NN) {
            const int deg = hist[g];
            const int rbase = scanb[g] - deg;

            // self logit from LDS
            float v2 = ass[g] + ads[g];
            v2 = v2 > 0.f ? v2 : NEG * v2;
            const float exs = __expf(v2);

            // self row (8 consecutive nodes per wave -> 1KB coalesced)
            uint4 hp = *(const uint4*)(h2 + ((size_t)node << 6) + (cq << 3));

            // 2-deep rolling prefetch over the node's full edge list
            float eA = 0.f, eB = 0.f;
            uint4 gA = make_uint4(0, 0, 0, 0), gB = make_uint4(0, 0, 0, 0);
            if (0 < deg) {
                const unsigned p = srtex[rbase];          // 8-lane broadcast
                const int s = (int)(p & 0xffffu);
                eA = __half2float(__ushort_as_half((unsigned short)(p >> 16)));
                gA = *(const uint4*)(h2 + ((size_t)s << 6) + (cq << 3));
            }
            if (1 < deg) {
                const unsigned p = srtex[rbase + 1];
                const int s = (int)(p & 0xffffu);
                eB = __half2float(__ushort_as_half((unsigned short)(p >> 16)));
                gB = *(const uint4*)(h2 + ((size_t)s << 6) + (cq << 3));
            }

            float acc[8];
            {
                const __half2* hh = (const __half2*)&hp;
#pragma unroll
                for (int j = 0; j < 4; ++j) {
                    float2 f = __half22float2(hh[j]);
                    acc[2 * j]     = exs * f.x;
                    acc[2 * j + 1] = exs * f.y;
                }
            }
            float den = exs;   // identical in all 8 lanes of the group

            for (int i = 0; i < deg; ++i) {
                float eC = 0.f; uint4 gC = make_uint4(0, 0, 0, 0);
                if (i + 2 < deg) {
                    const unsigned p = srtex[rbase + i + 2];
                    const int s = (int)(p & 0xffffu);
                    eC = __half2float(__ushort_as_half((unsigned short)(p >> 16)));
                    gC = *(const uint4*)(h2 + ((size_t)s << 6) + (cq << 3));
                }
                {
                    const __half2* gh = (const __half2*)&gA;
#pragma unroll
                    for (int j = 0; j < 4; ++j) {
                        float2 f = __half22float2(gh[j]);
                        acc[2 * j]     += eA * f.x;
                        acc[2 * j + 1] += eA * f.y;
                    }
                    den += eA;
                }
                eA = eB; gA = gB;
                eB = eC; gB = gC;
            }

            const float inv = 1.f / den;
            const float4 b0 = *(const float4*)(bias + (cq << 3));
            const float4 b1 = *(const float4*)(bias + (cq << 3) + 4);
            float4 o0, o1;
            o0.x = acc[0] * inv + b0.x; o0.y = acc[1] * inv + b0.y;
            o0.z = acc[2] * inv + b0.z; o0.w = acc[3] * inv + b0.w;
            o1.x = acc[4] * inv + b1.x; o1.y = acc[5] * inv + b1.y;
            o1.z = acc[6] * inv + b1.z; o1.w = acc[7] * inv + b1.w;
            // wave writes 8 consecutive nodes x 256B = 2KB contiguous
            float* op = out + ((size_t)node << 6) + (cq << 3);
            *(float4*)op = o0;
            *(float4*)(op + 4) = o1;
        }
    }
}

extern "C" void kernel_launch(void* const* d_in, const int* in_sizes, int n_in,
                              void* d_out, int out_size, void* d_ws, size_t ws_size,
                              hipStream_t stream) {
    const float* x       = (const float*)d_in[0];
    const int*   eidx    = (const int*)d_in[1];   // [2, NE] row-major
    const float* W       = (const float*)d_in[2];
    const float* att_src = (const float*)d_in[3];
    const float* att_dst = (const float*)d_in[4];
    const float* bias    = (const float*)d_in[5];
    float* out = (float*)d_out;

    // ws: h2 [NN*64 fp16 = 6.4MB] | gbucket [391*2560*4 = 4.0MB]
    //   | a_src [NN] | a_dst [NN] | bucket_cur [NBUCK]
    unsigned short* h2 = (unsigned short*)d_ws;
    int*   gbucket = (int*)((char*)d_ws + (size_t)NN * OUT_DIM * 2);
    float* a_src   = (float*)(gbucket + (size_t)NBUCK * HALFCAP);
    float* a_dst   = a_src + NN;
    int*   bucket_cur = (int*)(a_dst + NN);

    const int* src = eidx;
    const int* dst = eidx + NE;

    gat_zero<<<1, 512, 0, stream>>>(bucket_cur);
    gat_gemm_bin<<<GEMM_BLOCKS + BIN_BLOCKS, 512, 0, stream>>>(
        x, W, att_src, att_dst, src, dst, h2, a_src, a_dst, gbucket, bucket_cur);
    gat_sortagg<<<NBUCK, 1024, 0, stream>>>(
        gbucket, bucket_cur, (const __half*)h2, a_src, a_dst, bias, out);
}